// Round 16
// baseline (40.801 us; speedup 1.0000x reference)
//
#include <hip/hip_runtime.h>
#include <hip/hip_bf16.h>

typedef __attribute__((ext_vector_type(8))) short short8;
typedef __attribute__((ext_vector_type(4))) float f32x4;

#define NQ 32      // queries
#define NM 32      // query tokens
#define NH 128     // head dim
#define ND 512     // docs
#define NN 180     // doc tokens
#define NTMAX 12   // max compacted n-tiles (192 rows)

static __device__ __forceinline__ unsigned short f2bf(float x) {
  __hip_bfloat16 h = __float2bfloat16(x);
  return __builtin_bit_cast(unsigned short, h);
}

static __device__ __forceinline__ uint4 pack8(float4 a, float4 b) {
  unsigned int x = (unsigned)f2bf(a.x) | ((unsigned)f2bf(a.y) << 16);
  unsigned int y = (unsigned)f2bf(a.z) | ((unsigned)f2bf(a.w) << 16);
  unsigned int z = (unsigned)f2bf(b.x) | ((unsigned)f2bf(b.y) << 16);
  unsigned int u = (unsigned)f2bf(b.z) | ((unsigned)f2bf(b.w) << 16);
  return make_uint4(x, y, z, u);
}

// Fragment layout (16x16x32 bf16, swapped operands): element (lane,j) of tile
// (t, ks) = M[t*16 + (lane&15)][ks*32 + (lane>>4)*8 + j], stored 16B/lane.
//
// SINGLE fused kernel: 512 blocks x 512 thr (8 waves), one block per doc.
//  1) compaction map (ballot prefix-scan over the 180 mask flags)
//  2) stage compacted VALID rows -> LDS as bf16 MFMA-frag tiles (R14's proven
//     loop; pad rows = 0; no mask multiply needed for valid rows)
//  3) each wave builds its own Q fragments IN-REGISTER from raw fp32 Q
//     (L2/L3-hot 512KB shared across all 512 blocks; one fragment packed at a
//     time to keep temps small) -> no prep_q kernel, no Qb workspace, no
//     launch dependency. Then 2 sequential query pairs (#pragma unroll 1).
// VGPR must stay <=128: 129 drops to 1 block/CU (8 waves need 2 blocks/CU for
// 4 waves/SIMD; VGPR pool 512/SIMD). __launch_bounds__(512,4) enforces.
__global__ __launch_bounds__(512, 4) void fused_maxsim(
    const float* __restrict__ Q, const float* __restrict__ D,
    const int* __restrict__ qmask, const int* __restrict__ dmask,
    float* __restrict__ out) {
  __shared__ unsigned char Dlds[NTMAX * 4096];   // 49152 B frag-order tiles
  __shared__ unsigned short mapinv[192];
  __shared__ int wtot[4];
  const int d = blockIdx.x;
  const int tid = threadIdx.x;
  const int lane = tid & 63;
  const int w = tid >> 6;
  const float NEG = -__builtin_inff();

  // ---- 1) compaction map ----
  int flag = 0, pre = 0;
  if (tid < NN) flag = dmask[d * NN + tid];
  if (tid < 192) {   // waves 0..2
    unsigned long long bal = __ballot(flag != 0);
    pre = __popcll(bal & ((1ull << lane) - 1ull));
    if (lane == 63) wtot[w] = pre + (flag ? 1 : 0);
  }
  __syncthreads();
  const int cnt = wtot[0] + wtot[1] + wtot[2];
  if (tid < 192 && flag) {
    int base = (w >= 1 ? wtot[0] : 0) + (w >= 2 ? wtot[1] : 0);
    mapinv[pre + base] = (unsigned short)tid;
  }
  __syncthreads();

  // ---- 2) stage compacted bf16 frag tiles (R14's proven loop) ----
  const int ntc = (cnt + 15) >> 4;
  for (int s = tid; s < ntc * 256; s += 512) {
    int nt = s >> 8, ks = (s >> 6) & 3, ln = s & 63;
    int bl2 = ln & 15, bg2 = ln >> 4;
    int dr = nt * 16 + bl2;
    uint4 o = make_uint4(0u, 0u, 0u, 0u);
    if (dr < cnt) {
      int sr = mapinv[dr];
      const float4* p = reinterpret_cast<const float4*>(D) +
                        (size_t)(d * NN + sr) * 32 + ks * 8 + bg2 * 2;
      o = pack8(p[0], p[1]);
    }
    *reinterpret_cast<uint4*>(&Dlds[(size_t)s * 16]) = o;
  }
  __syncthreads();

  // ---- 3) compute: wave w owns queries w*4 .. w*4+3, two sequential pairs ----
  const int bl = lane & 15;
  const int bg = lane >> 4;

  #pragma unroll 1
  for (int p = 0; p < 2; ++p) {
    const int q0 = w * 4 + p * 2;

    // build Q fragments in-register from raw fp32 Q (one frag at a time)
    short8 Qf[2][2][4];  // [qi][mt][ks], 64 VGPR
    #pragma unroll
    for (int qi = 0; qi < 2; ++qi)
      #pragma unroll
      for (int mt = 0; mt < 2; ++mt) {
        const int row = mt * 16 + bl;
        const float qm = (float)qmask[(q0 + qi) * NM + row];
        const float* qsrc = Q + ((q0 + qi) * NM + row) * NH + bg * 8;
        #pragma unroll
        for (int ks = 0; ks < 4; ++ks) {
          float4 a = *reinterpret_cast<const float4*>(qsrc + ks * 32);
          float4 b = *reinterpret_cast<const float4*>(qsrc + ks * 32 + 4);
          a.x *= qm; a.y *= qm; a.z *= qm; a.w *= qm;
          b.x *= qm; b.y *= qm; b.z *= qm; b.w *= qm;
          uint4 pk = pack8(a, b);
          Qf[qi][mt][ks] = __builtin_bit_cast(short8, pk);
        }
      }

    float run[2][2];
    #pragma unroll
    for (int qi = 0; qi < 2; ++qi)
      #pragma unroll
      for (int mt = 0; mt < 2; ++mt) run[qi][mt] = NEG;

    #pragma unroll 2
    for (int nt = 0; nt < ntc; ++nt) {
      short8 Da[4];
      #pragma unroll
      for (int ks = 0; ks < 4; ++ks)
        Da[ks] = *reinterpret_cast<const short8*>(
            &Dlds[((nt * 4 + ks) << 10) + (lane << 4)]);

      f32x4 acc[2][2];
      #pragma unroll
      for (int qi = 0; qi < 2; ++qi)
        #pragma unroll
        for (int mt = 0; mt < 2; ++mt) acc[qi][mt] = (f32x4){0.f, 0.f, 0.f, 0.f};

      #pragma unroll
      for (int ks = 0; ks < 4; ++ks)
        #pragma unroll
        for (int qi = 0; qi < 2; ++qi)
          #pragma unroll
          for (int mt = 0; mt < 2; ++mt)
            acc[qi][mt] = __builtin_amdgcn_mfma_f32_16x16x32_bf16(
                Da[ks], Qf[qi][mt][ks], acc[qi][mt], 0, 0, 0);

      if (nt * 16 + 16 > cnt) {
        // tail tile: lane holds rows nt*16 + bg*4 + j; valid iff j < rlim
        const int rlim = cnt - nt * 16 - bg * 4;
        #pragma unroll
        for (int qi = 0; qi < 2; ++qi)
          #pragma unroll
          for (int mt = 0; mt < 2; ++mt) {
            float vmax = NEG;
            #pragma unroll
            for (int j = 0; j < 4; ++j) {
              float v = (j < rlim) ? acc[qi][mt][j] : NEG;
              vmax = fmaxf(vmax, v);
            }
            run[qi][mt] = fmaxf(run[qi][mt], vmax);
          }
      } else {
        #pragma unroll
        for (int qi = 0; qi < 2; ++qi)
          #pragma unroll
          for (int mt = 0; mt < 2; ++mt) {
            float vmax = fmaxf(fmaxf(acc[qi][mt][0], acc[qi][mt][1]),
                               fmaxf(acc[qi][mt][2], acc[qi][mt][3]));
            run[qi][mt] = fmaxf(run[qi][mt], vmax);
          }
      }
    }

    // masked doc tokens inject an exact 0 into max_n
    if (cnt < NN) {
      #pragma unroll
      for (int qi = 0; qi < 2; ++qi)
        #pragma unroll
        for (int mt = 0; mt < 2; ++mt) run[qi][mt] = fmaxf(run[qi][mt], 0.f);
    }

    // reduction: xor16/32 max over n-quarters, xor1..8 sum over m
    #pragma unroll
    for (int qi = 0; qi < 2; ++qi) {
      float a = run[qi][0];   // m = lane&15
      float bb = run[qi][1];  // m = (lane&15)+16
      a = fmaxf(a, __shfl_xor(a, 16));
      a = fmaxf(a, __shfl_xor(a, 32));
      bb = fmaxf(bb, __shfl_xor(bb, 16));
      bb = fmaxf(bb, __shfl_xor(bb, 32));
      float s = a + bb;
      s += __shfl_xor(s, 1);
      s += __shfl_xor(s, 2);
      s += __shfl_xor(s, 4);
      s += __shfl_xor(s, 8);
      if (lane == 0) out[(q0 + qi) * ND + d] = s;
    }
  }
}

extern "C" void kernel_launch(void* const* d_in, const int* in_sizes, int n_in,
                              void* d_out, int out_size, void* d_ws, size_t ws_size,
                              hipStream_t stream) {
  const float* Q = (const float*)d_in[0];
  const float* D = (const float*)d_in[1];
  const int* qmask = (const int*)d_in[2];
  const int* dmask = (const int*)d_in[3];
  float* out = (float*)d_out;

  fused_maxsim<<<ND, 512, 0, stream>>>(Q, D, qmask, dmask, out);
}

// Round 17
// 29.261 us; speedup vs baseline: 1.3944x; 1.3944x over previous
//
#include <hip/hip_runtime.h>
#include <hip/hip_bf16.h>

typedef __attribute__((ext_vector_type(8))) short short8;
typedef __attribute__((ext_vector_type(4))) float f32x4;

#define NQ 32      // queries
#define NM 32      // query tokens
#define NH 128     // head dim
#define ND 512     // docs
#define NN 180     // doc tokens
#define NTMAX 12   // max compacted n-tiles (192 rows)

#define QFRAG_BYTES (NQ * 2 * 4 * 64 * 16)              // 256 KB
#define DCBLK_BYTES (NTMAX * 4 * 64 * 16)               // 49152 B per doc
#define DC_OFF      QFRAG_BYTES
#define CNT_OFF     (DC_OFF + ND * DCBLK_BYTES)         // ~25.4 MB total

static __device__ __forceinline__ unsigned short f2bf(float x) {
  __hip_bfloat16 h = __float2bfloat16(x);
  return __builtin_bit_cast(unsigned short, h);
}

static __device__ __forceinline__ uint4 pack8m(const float* v, float m) {
  unsigned int a = (unsigned)f2bf(v[0] * m) | ((unsigned)f2bf(v[1] * m) << 16);
  unsigned int b = (unsigned)f2bf(v[2] * m) | ((unsigned)f2bf(v[3] * m) << 16);
  unsigned int c = (unsigned)f2bf(v[4] * m) | ((unsigned)f2bf(v[5] * m) << 16);
  unsigned int e = (unsigned)f2bf(v[6] * m) | ((unsigned)f2bf(v[7] * m) << 16);
  return make_uint4(a, b, c, e);
}

static __device__ __forceinline__ uint4 pack8(float4 a, float4 b) {
  unsigned int x = (unsigned)f2bf(a.x) | ((unsigned)f2bf(a.y) << 16);
  unsigned int y = (unsigned)f2bf(a.z) | ((unsigned)f2bf(a.w) << 16);
  unsigned int z = (unsigned)f2bf(b.x) | ((unsigned)f2bf(b.y) << 16);
  unsigned int u = (unsigned)f2bf(b.z) | ((unsigned)f2bf(b.w) << 16);
  return make_uint4(x, y, z, u);
}

// Fragment layout (16x16x32 bf16, swapped operands): element (lane,j) of tile
// (t, ks) = M[t*16 + (lane&15)][ks*32 + (lane>>4)*8 + j], stored 16B/lane.
//
// prep (R12-proven): blocks 0..511 = doc d -> compaction map (ballot
// prefix-scan) then compacted bf16 frag tiles Dc[d] (valid rows only, no mask
// mul needed) + cnt[d]. Blocks 512..575 = Q fragments (masked bf16).
// All irregular gather/pack VALU lives HERE (memory-bound, high occupancy);
// maxsim is left pure streaming MFMA.
__global__ __launch_bounds__(256) void prep_kernel(
    const float* __restrict__ Q, const float* __restrict__ D,
    const int* __restrict__ qmask, const int* __restrict__ dmask,
    unsigned short* __restrict__ Qb, char* __restrict__ Dc,
    int* __restrict__ cnt_arr) {
  const int tid = threadIdx.x;

  if (blockIdx.x < ND) {
    __shared__ unsigned short mapinv[192];
    __shared__ int wtot[3];
    const int d = blockIdx.x;              // XCD = d%8 == maxsim reader's XCD
    const int lane = tid & 63;
    const int w = tid >> 6;

    int flag = 0, pre = 0;
    if (tid < NN) flag = dmask[d * NN + tid];
    if (tid < 192) {
      unsigned long long b = __ballot(flag != 0);
      pre = __popcll(b & ((1ull << lane) - 1ull));
      if (lane == 63) wtot[w] = pre + (flag ? 1 : 0);
    }
    __syncthreads();
    const int cnt = wtot[0] + wtot[1] + wtot[2];
    if (tid < 192 && flag) {
      int base = (w >= 1 ? wtot[0] : 0) + (w >= 2 ? wtot[1] : 0);
      mapinv[pre + base] = (unsigned short)tid;
    }
    __syncthreads();

    const int ntc = (cnt + 15) >> 4;
    uint4* dcout = reinterpret_cast<uint4*>(Dc + (size_t)d * DCBLK_BYTES);
    for (int s = tid; s < ntc * 256; s += 256) {
      int nt = s >> 8, ks = (s >> 6) & 3, ln = s & 63;
      int bl = ln & 15, bg = ln >> 4;
      int dr = nt * 16 + bl;
      uint4 o = make_uint4(0u, 0u, 0u, 0u);
      if (dr < cnt) {
        int sr = mapinv[dr];
        const float4* p = reinterpret_cast<const float4*>(D) +
                          (size_t)(d * NN + sr) * 32 + ks * 8 + bg * 2;
        o = pack8(p[0], p[1]);
      }
      dcout[(size_t)nt * 256 + ks * 64 + ln] = o;
    }
    if (tid == 0) cnt_arr[d] = cnt;
  } else {
    int idx = (blockIdx.x - ND) * 256 + tid;   // 16384 fragment-lanes
    int lane = idx & 63;
    int ks = (idx >> 6) & 3;
    int mt = (idx >> 8) & 1;
    int q  = idx >> 9;
    int row = mt * 16 + (lane & 15);
    int k0  = ks * 32 + (lane >> 4) * 8;
    const float* src = Q + (q * NM + row) * NH + k0;
    float v[8];
    *reinterpret_cast<float4*>(&v[0]) = *reinterpret_cast<const float4*>(src);
    *reinterpret_cast<float4*>(&v[4]) = *reinterpret_cast<const float4*>(src + 4);
    float m = (float)qmask[q * NM + row];
    reinterpret_cast<uint4*>(Qb)[idx] = pack8m(v, m);
  }
}

// maxsim: 512 blocks x 512 thr (8 waves), block = doc (same XCD as its prep
// writer -> Dc L2-hot, 1.57 MB/XCD). NO LDS, NO barriers, NO pack VALU:
// Da fragments are direct coalesced 16B/lane loads linear in nt (prefetchable
// by unroll-2), then 16 MFMA + fold. Wave w owns queries w*4..w*4+3 as two
// sequential pairs (#pragma unroll 1 -> one pair's ~120 VGPR live).
// __launch_bounds__(512,4) caps 128 VGPR -> 2 blocks/CU, 4 waves/SIMD.
__global__ __launch_bounds__(512, 4) void maxsim_kernel(
    const char* __restrict__ Dc, const int* __restrict__ cnt_arr,
    const unsigned short* __restrict__ Qb, float* __restrict__ out) {
  const int d = blockIdx.x;
  const int tid = threadIdx.x;
  const int lane = tid & 63;
  const int w = tid >> 6;
  const int bg = lane >> 4;
  const float NEG = -__builtin_inff();

  const int cnt = cnt_arr[d];
  const int ntc = (cnt + 15) >> 4;
  const char* Dcd = Dc + (size_t)d * DCBLK_BYTES;

  #pragma unroll 1
  for (int p = 0; p < 2; ++p) {
    const int q0 = w * 4 + p * 2;

    short8 Qf[2][2][4];  // [qi][mt][ks], 64 VGPR, plain loads (stay resident)
    #pragma unroll
    for (int qi = 0; qi < 2; ++qi)
      #pragma unroll
      for (int mt = 0; mt < 2; ++mt)
        #pragma unroll
        for (int ks = 0; ks < 4; ++ks)
          Qf[qi][mt][ks] = *reinterpret_cast<const short8*>(
              reinterpret_cast<const char*>(Qb) +
              ((((q0 + qi) * 2 + mt) * 4 + ks) << 10) + (lane << 4));

    float run[2][2];
    #pragma unroll
    for (int qi = 0; qi < 2; ++qi)
      #pragma unroll
      for (int mt = 0; mt < 2; ++mt) run[qi][mt] = NEG;

    #pragma unroll 2
    for (int nt = 0; nt < ntc; ++nt) {
      short8 Da[4];
      #pragma unroll
      for (int ks = 0; ks < 4; ++ks)
        Da[ks] = *reinterpret_cast<const short8*>(
            Dcd + (((nt * 4 + ks) << 10) + (lane << 4)));

      f32x4 acc[2][2];
      #pragma unroll
      for (int qi = 0; qi < 2; ++qi)
        #pragma unroll
        for (int mt = 0; mt < 2; ++mt) acc[qi][mt] = (f32x4){0.f, 0.f, 0.f, 0.f};

      #pragma unroll
      for (int ks = 0; ks < 4; ++ks)
        #pragma unroll
        for (int qi = 0; qi < 2; ++qi)
          #pragma unroll
          for (int mt = 0; mt < 2; ++mt)
            acc[qi][mt] = __builtin_amdgcn_mfma_f32_16x16x32_bf16(
                Da[ks], Qf[qi][mt][ks], acc[qi][mt], 0, 0, 0);

      if (nt * 16 + 16 > cnt) {
        // tail tile: lane holds rows nt*16 + bg*4 + j; valid iff j < rlim
        const int rlim = cnt - nt * 16 - bg * 4;
        #pragma unroll
        for (int qi = 0; qi < 2; ++qi)
          #pragma unroll
          for (int mt = 0; mt < 2; ++mt) {
            float vmax = NEG;
            #pragma unroll
            for (int j = 0; j < 4; ++j) {
              float v = (j < rlim) ? acc[qi][mt][j] : NEG;
              vmax = fmaxf(vmax, v);
            }
            run[qi][mt] = fmaxf(run[qi][mt], vmax);
          }
      } else {
        #pragma unroll
        for (int qi = 0; qi < 2; ++qi)
          #pragma unroll
          for (int mt = 0; mt < 2; ++mt) {
            float vmax = fmaxf(fmaxf(acc[qi][mt][0], acc[qi][mt][1]),
                               fmaxf(acc[qi][mt][2], acc[qi][mt][3]));
            run[qi][mt] = fmaxf(run[qi][mt], vmax);
          }
      }
    }

    // masked doc tokens inject an exact 0 into max_n
    if (cnt < NN) {
      #pragma unroll
      for (int qi = 0; qi < 2; ++qi)
        #pragma unroll
        for (int mt = 0; mt < 2; ++mt) run[qi][mt] = fmaxf(run[qi][mt], 0.f);
    }

    // reduction: xor16/32 max over n-quarters, xor1..8 sum over m
    #pragma unroll
    for (int qi = 0; qi < 2; ++qi) {
      float a = run[qi][0];   // m = lane&15
      float bb = run[qi][1];  // m = (lane&15)+16
      a = fmaxf(a, __shfl_xor(a, 16));
      a = fmaxf(a, __shfl_xor(a, 32));
      bb = fmaxf(bb, __shfl_xor(bb, 16));
      bb = fmaxf(bb, __shfl_xor(bb, 32));
      float s = a + bb;
      s += __shfl_xor(s, 1);
      s += __shfl_xor(s, 2);
      s += __shfl_xor(s, 4);
      s += __shfl_xor(s, 8);
      if (lane == 0) out[(q0 + qi) * ND + d] = s;
    }
  }
}

extern "C" void kernel_launch(void* const* d_in, const int* in_sizes, int n_in,
                              void* d_out, int out_size, void* d_ws, size_t ws_size,
                              hipStream_t stream) {
  const float* Q = (const float*)d_in[0];
  const float* D = (const float*)d_in[1];
  const int* qmask = (const int*)d_in[2];
  const int* dmask = (const int*)d_in[3];
  float* out = (float*)d_out;

  unsigned short* Qb = (unsigned short*)d_ws;
  char* Dc = (char*)d_ws + DC_OFF;
  int* cnt_arr = (int*)((char*)d_ws + CNT_OFF);

  prep_kernel<<<ND + 64, 256, 0, stream>>>(Q, D, qmask, dmask, Qb, Dc, cnt_arr);
  maxsim_kernel<<<ND, 512, 0, stream>>>(Dc, cnt_arr, Qb, out);
}

// Round 18
// 28.585 us; speedup vs baseline: 1.4273x; 1.0236x over previous
//
#include <hip/hip_runtime.h>
#include <hip/hip_bf16.h>

typedef __attribute__((ext_vector_type(8))) short short8;
typedef __attribute__((ext_vector_type(4))) float f32x4;

#define NQ 32      // queries
#define NM 32      // query tokens
#define NH 128     // head dim
#define ND 512     // docs
#define NN 180     // doc tokens
#define NTMAX 12   // max compacted n-tiles (192 rows)

#define QFRAG_BYTES (NQ * 2 * 4 * 64 * 16)              // 256 KB
#define DCBLK_BYTES (NTMAX * 4 * 64 * 16)               // 49152 B per doc
#define DC_OFF      QFRAG_BYTES
#define CNT_OFF     (DC_OFF + ND * DCBLK_BYTES)         // ~25.4 MB total

static __device__ __forceinline__ unsigned short f2bf(float x) {
  __hip_bfloat16 h = __float2bfloat16(x);
  return __builtin_bit_cast(unsigned short, h);
}

static __device__ __forceinline__ uint4 pack8m(const float* v, float m) {
  unsigned int a = (unsigned)f2bf(v[0] * m) | ((unsigned)f2bf(v[1] * m) << 16);
  unsigned int b = (unsigned)f2bf(v[2] * m) | ((unsigned)f2bf(v[3] * m) << 16);
  unsigned int c = (unsigned)f2bf(v[4] * m) | ((unsigned)f2bf(v[5] * m) << 16);
  unsigned int e = (unsigned)f2bf(v[6] * m) | ((unsigned)f2bf(v[7] * m) << 16);
  return make_uint4(a, b, c, e);
}

static __device__ __forceinline__ uint4 pack8(float4 a, float4 b) {
  unsigned int x = (unsigned)f2bf(a.x) | ((unsigned)f2bf(a.y) << 16);
  unsigned int y = (unsigned)f2bf(a.z) | ((unsigned)f2bf(a.w) << 16);
  unsigned int z = (unsigned)f2bf(b.x) | ((unsigned)f2bf(b.y) << 16);
  unsigned int u = (unsigned)f2bf(b.z) | ((unsigned)f2bf(b.w) << 16);
  return make_uint4(x, y, z, u);
}

// async 16B global->LDS copy (gfx950 global_load_lds, width 16)
static __device__ __forceinline__ void async_copy16(const void* g, void* l) {
  __builtin_amdgcn_global_load_lds(
      (const __attribute__((address_space(1))) unsigned int*)g,
      (__attribute__((address_space(3))) unsigned int*)l, 16, 0, 0);
}

// Fragment layout (16x16x32 bf16, swapped operands): element (lane,j) of tile
// (t, ks) = M[t*16 + (lane&15)][ks*32 + (lane>>4)*8 + j], stored 16B/lane.
//
// prep (R17-proven): blocks 0..511 = doc d -> compaction map (ballot
// prefix-scan) then compacted bf16 frag tiles Dc[d] (valid rows only) + cnt[d].
// Blocks 512..575 = Q fragments (masked bf16). All gather/pack VALU lives here.
__global__ __launch_bounds__(256) void prep_kernel(
    const float* __restrict__ Q, const float* __restrict__ D,
    const int* __restrict__ qmask, const int* __restrict__ dmask,
    unsigned short* __restrict__ Qb, char* __restrict__ Dc,
    int* __restrict__ cnt_arr) {
  const int tid = threadIdx.x;

  if (blockIdx.x < ND) {
    __shared__ unsigned short mapinv[192];
    __shared__ int wtot[3];
    const int d = blockIdx.x;              // XCD = d%8 == maxsim reader's XCD
    const int lane = tid & 63;
    const int w = tid >> 6;

    int flag = 0, pre = 0;
    if (tid < NN) flag = dmask[d * NN + tid];
    if (tid < 192) {
      unsigned long long b = __ballot(flag != 0);
      pre = __popcll(b & ((1ull << lane) - 1ull));
      if (lane == 63) wtot[w] = pre + (flag ? 1 : 0);
    }
    __syncthreads();
    const int cnt = wtot[0] + wtot[1] + wtot[2];
    if (tid < 192 && flag) {
      int base = (w >= 1 ? wtot[0] : 0) + (w >= 2 ? wtot[1] : 0);
      mapinv[pre + base] = (unsigned short)tid;
    }
    __syncthreads();

    const int ntc = (cnt + 15) >> 4;
    uint4* dcout = reinterpret_cast<uint4*>(Dc + (size_t)d * DCBLK_BYTES);
    for (int s = tid; s < ntc * 256; s += 256) {
      int nt = s >> 8, ks = (s >> 6) & 3, ln = s & 63;
      int bl = ln & 15, bg = ln >> 4;
      int dr = nt * 16 + bl;
      uint4 o = make_uint4(0u, 0u, 0u, 0u);
      if (dr < cnt) {
        int sr = mapinv[dr];
        const float4* p = reinterpret_cast<const float4*>(D) +
                          (size_t)(d * NN + sr) * 32 + ks * 8 + bg * 2;
        o = pack8(p[0], p[1]);
      }
      dcout[(size_t)nt * 256 + ks * 64 + ln] = o;
    }
    if (tid == 0) cnt_arr[d] = cnt;
  } else {
    int idx = (blockIdx.x - ND) * 256 + tid;   // 16384 fragment-lanes
    int lane = idx & 63;
    int ks = (idx >> 6) & 3;
    int mt = (idx >> 8) & 1;
    int q  = idx >> 9;
    int row = mt * 16 + (lane & 15);
    int k0  = ks * 32 + (lane >> 4) * 8;
    const float* src = Q + (q * NM + row) * NH + k0;
    float v[8];
    *reinterpret_cast<float4*>(&v[0]) = *reinterpret_cast<const float4*>(src);
    *reinterpret_cast<float4*>(&v[4]) = *reinterpret_cast<const float4*>(src + 4);
    float m = (float)qmask[q * NM + row];
    reinterpret_cast<uint4*>(Qb)[idx] = pack8m(v, m);
  }
}

// maxsim: 512 blocks x 512 thr (8 waves), block = doc (same XCD as its prep
// writer -> Dc L2-hot). Stage = 6 async global_load_lds (16B/lane; LDS dest is
// exactly wave-uniform-base + lane*16 by construction of the frag layout) ->
// ZERO staging VALU/VGPR; pad tiles staged but never read (branch-free).
// Compute = R14's proven body: wave w owns queries w*4..w*4+3 as two
// sequential pairs; Qf plain loads (stay resident); in-loop tail masking.
// __launch_bounds__(512,4) caps 128 VGPR -> 2 blocks/CU, 4 waves/SIMD.
__global__ __launch_bounds__(512, 4) void maxsim_kernel(
    const char* __restrict__ Dc, const int* __restrict__ cnt_arr,
    const unsigned short* __restrict__ Qb, float* __restrict__ out) {
  __shared__ __attribute__((aligned(16))) unsigned char Dlds[NTMAX * 4096];
  const int d = blockIdx.x;
  const int tid = threadIdx.x;
  const int lane = tid & 63;
  const int w = tid >> 6;
  const int bg = lane >> 4;
  const float NEG = -__builtin_inff();

  const int cnt = cnt_arr[d];
  const int ntc = (cnt + 15) >> 4;
  const char* Dcd = Dc + (size_t)d * DCBLK_BYTES;

  // ---- async stage: all 12 tiles, 16B per lane per step ----
  #pragma unroll
  for (int u = 0; u < 6; ++u) {
    const int off = (u * 512 + tid) * 16;
    async_copy16(Dcd + off, &Dlds[off]);
  }
  __syncthreads();   // drains vmcnt before any wave reads LDS

  #pragma unroll 1
  for (int p = 0; p < 2; ++p) {
    const int q0 = w * 4 + p * 2;

    short8 Qf[2][2][4];  // [qi][mt][ks], 64 VGPR, plain loads (stay resident)
    #pragma unroll
    for (int qi = 0; qi < 2; ++qi)
      #pragma unroll
      for (int mt = 0; mt < 2; ++mt)
        #pragma unroll
        for (int ks = 0; ks < 4; ++ks)
          Qf[qi][mt][ks] = *reinterpret_cast<const short8*>(
              reinterpret_cast<const char*>(Qb) +
              ((((q0 + qi) * 2 + mt) * 4 + ks) << 10) + (lane << 4));

    float run[2][2];
    #pragma unroll
    for (int qi = 0; qi < 2; ++qi)
      #pragma unroll
      for (int mt = 0; mt < 2; ++mt) run[qi][mt] = NEG;

    #pragma unroll 2
    for (int nt = 0; nt < ntc; ++nt) {
      short8 Da[4];
      #pragma unroll
      for (int ks = 0; ks < 4; ++ks)
        Da[ks] = *reinterpret_cast<const short8*>(
            &Dlds[((nt * 4 + ks) << 10) + (lane << 4)]);

      f32x4 acc[2][2];
      #pragma unroll
      for (int qi = 0; qi < 2; ++qi)
        #pragma unroll
        for (int mt = 0; mt < 2; ++mt) acc[qi][mt] = (f32x4){0.f, 0.f, 0.f, 0.f};

      #pragma unroll
      for (int ks = 0; ks < 4; ++ks)
        #pragma unroll
        for (int qi = 0; qi < 2; ++qi)
          #pragma unroll
          for (int mt = 0; mt < 2; ++mt)
            acc[qi][mt] = __builtin_amdgcn_mfma_f32_16x16x32_bf16(
                Da[ks], Qf[qi][mt][ks], acc[qi][mt], 0, 0, 0);

      if (nt * 16 + 16 > cnt) {
        // tail tile: lane holds rows nt*16 + bg*4 + j; valid iff j < rlim
        const int rlim = cnt - nt * 16 - bg * 4;
        #pragma unroll
        for (int qi = 0; qi < 2; ++qi)
          #pragma unroll
          for (int mt = 0; mt < 2; ++mt) {
            float vmax = NEG;
            #pragma unroll
            for (int j = 0; j < 4; ++j) {
              float v = (j < rlim) ? acc[qi][mt][j] : NEG;
              vmax = fmaxf(vmax, v);
            }
            run[qi][mt] = fmaxf(run[qi][mt], vmax);
          }
      } else {
        #pragma unroll
        for (int qi = 0; qi < 2; ++qi)
          #pragma unroll
          for (int mt = 0; mt < 2; ++mt) {
            float vmax = fmaxf(fmaxf(acc[qi][mt][0], acc[qi][mt][1]),
                               fmaxf(acc[qi][mt][2], acc[qi][mt][3]));
            run[qi][mt] = fmaxf(run[qi][mt], vmax);
          }
      }
    }

    // masked doc tokens inject an exact 0 into max_n
    if (cnt < NN) {
      #pragma unroll
      for (int qi = 0; qi < 2; ++qi)
        #pragma unroll
        for (int mt = 0; mt < 2; ++mt) run[qi][mt] = fmaxf(run[qi][mt], 0.f);
    }

    // reduction: xor16/32 max over n-quarters, xor1..8 sum over m
    #pragma unroll
    for (int qi = 0; qi < 2; ++qi) {
      float a = run[qi][0];   // m = lane&15
      float bb = run[qi][1];  // m = (lane&15)+16
      a = fmaxf(a, __shfl_xor(a, 16));
      a = fmaxf(a, __shfl_xor(a, 32));
      bb = fmaxf(bb, __shfl_xor(bb, 16));
      bb = fmaxf(bb, __shfl_xor(bb, 32));
      float s = a + bb;
      s += __shfl_xor(s, 1);
      s += __shfl_xor(s, 2);
      s += __shfl_xor(s, 4);
      s += __shfl_xor(s, 8);
      if (lane == 0) out[(q0 + qi) * ND + d] = s;
    }
  }
}

extern "C" void kernel_launch(void* const* d_in, const int* in_sizes, int n_in,
                              void* d_out, int out_size, void* d_ws, size_t ws_size,
                              hipStream_t stream) {
  const float* Q = (const float*)d_in[0];
  const float* D = (const float*)d_in[1];
  const int* qmask = (const int*)d_in[2];
  const int* dmask = (const int*)d_in[3];
  float* out = (float*)d_out;

  unsigned short* Qb = (unsigned short*)d_ws;
  char* Dc = (char*)d_ws + DC_OFF;
  int* cnt_arr = (int*)((char*)d_ws + CNT_OFF);

  prep_kernel<<<ND + 64, 256, 0, stream>>>(Q, D, qmask, dmask, Qb, Dc, cnt_arr);
  maxsim_kernel<<<ND, 512, 0, stream>>>(Dc, cnt_arr, Qb, out);
}